// Round 1
// baseline (3317.342 us; speedup 1.0000x reference)
//
#include <hip/hip_runtime.h>

// Problem constants (match reference)
#define C 80
#define P 30000
#define G 800
#define BS 256
#define PBLK ((P + BS - 1) / BS)   // 118

// ---------------- init: counters + first[] = P ----------------
__global__ void init_kernel(int* __restrict__ validCount,
                            int* __restrict__ tpCount,
                            int* __restrict__ first) {
    int idx = blockIdx.x * blockDim.x + threadIdx.x;
    if (idx < C * G) first[idx] = P;
    if (idx < C) { validCount[idx] = 0; tpCount[idx] = 0; }
}

// ---------------- match: per pred, best IoU + argmax gt ----------------
// Replicates jnp semantics exactly: strict-> update == argmax first occurrence,
// valid = best_iou > 0.5 (strict). __f*_rn blocks FMA contraction so f32
// results are bit-identical to the numpy reference. inter==0 => iou=+0 exactly
// (denominator is strictly positive), so the division skip is bit-exact.
__global__ void match_kernel(const float* __restrict__ pred,
                             const float* __restrict__ gt,
                             int* __restrict__ validCount,
                             int2* __restrict__ validRec) {
    __shared__ float4 sbox[G];
    __shared__ float  sarea[G];
    const int c = blockIdx.y;
    const int tid = threadIdx.x;
    for (int g = tid; g < G; g += BS) {
        const float* gb = gt + (size_t)(c * G + g) * 7;
        float x1 = gb[3], y1 = gb[4], x2 = gb[5], y2 = gb[6];
        sbox[g] = make_float4(x1, y1, x2, y2);
        sarea[g] = __fmul_rn(__fsub_rn(x2, x1), __fsub_rn(y2, y1));
    }
    __syncthreads();
    const int p = blockIdx.x * BS + tid;
    if (p >= P) return;
    const float* pb = pred + (size_t)(c * P + p) * 7;
    const float ax1 = pb[3], ay1 = pb[4], ax2 = pb[5], ay2 = pb[6];
    const float areaA = __fmul_rn(__fsub_rn(ax2, ax1), __fsub_rn(ay2, ay1));
    float best = -1.0f;
    int   match = 0;
    for (int g = 0; g < G; ++g) {
        float4 b = sbox[g];
        float lx = fmaxf(ax1, b.x), ly = fmaxf(ay1, b.y);
        float rx = fminf(ax2, b.z), ry = fminf(ay2, b.w);
        float wx = fmaxf(__fsub_rn(rx, lx), 0.0f);
        float wy = fmaxf(__fsub_rn(ry, ly), 0.0f);
        float inter = __fmul_rn(wx, wy);
        float iou = 0.0f;
        if (inter > 0.0f) {
            float denom = __fadd_rn(__fsub_rn(__fadd_rn(areaA, sarea[g]), inter), 1e-9f);
            iou = __fdiv_rn(inter, denom);
        }
        if (iou > best) { best = iou; match = g; }
    }
    if (best > 0.5f) {
        int slot = atomicAdd(&validCount[c], 1);
        validRec[(size_t)c * P + slot] = make_int2(p, match);
    }
}

// ---------------- rank: exact sorted position of each valid pred ----------------
// rank = #{q : s_q > s_v} + #{q : s_q == s_v && q < p_v}  (stable argsort, desc)
// Ranks form a strict total order => unique per pred. Also scatter-min into first[gt].
__global__ void rank_kernel(const float* __restrict__ pred,
                            const int*  __restrict__ validCount,
                            const int2* __restrict__ validRec,
                            int* __restrict__ validRank,
                            int* __restrict__ first) {
    __shared__ float ss[BS];
    const int c = blockIdx.y;
    const int V = validCount[c];
    if ((int)(blockIdx.x * BS) >= V) return;   // block-uniform early exit
    const int tid = threadIdx.x;
    const int v = blockIdx.x * BS + tid;
    const bool active = v < V;
    int myp = 0, mym = 0; float sv = 0.0f;
    if (active) {
        int2 rec = validRec[(size_t)c * P + v];
        myp = rec.x; mym = rec.y;
        sv = pred[(size_t)(c * P + myp) * 7 + 2];
    }
    int cnt = 0;
    for (int t = 0; t < P; t += BS) {
        int q = t + tid;
        ss[tid] = (q < P) ? pred[(size_t)(c * P + q) * 7 + 2] : -1.0f;
        __syncthreads();
        int tl = min(BS, P - t);
        if (active) {
            for (int j = 0; j < tl; ++j) {
                float sq = ss[j];
                int   qq = t + j;
                cnt += (sq > sv || (sq == sv && qq < myp)) ? 1 : 0;
            }
        }
        __syncthreads();
    }
    if (active) {
        validRank[(size_t)c * P + v] = cnt;
        atomicMin(&first[c * G + mym], cnt);
    }
}

// ---------------- tp: valid pred whose rank == first[its gt] is the TP ----------------
__global__ void tp_kernel(const int*  __restrict__ validCount,
                          const int2* __restrict__ validRec,
                          const int*  __restrict__ validRank,
                          const int*  __restrict__ first,
                          int* __restrict__ tpCount,
                          int* __restrict__ tpRank) {
    const int c = blockIdx.y;
    const int V = validCount[c];
    const int v = blockIdx.x * BS + threadIdx.x;
    if (v >= V) return;
    int2 rec = validRec[(size_t)c * P + v];
    int r = validRank[(size_t)c * P + v];
    if (first[c * G + rec.y] == r) {
        int t = atomicAdd(&tpCount[c], 1);
        tpRank[c * G + t] = r;   // <= G entries (one TP per gt max)
    }
}

// ---------------- ap: per class, from TP ranks only ----------------
// precision[i] = ctp[i]/(i+1) exactly (ctp+cfp == i+1; the +1e-9 rounds away in f32).
// TP at sorted pos i (i>=1) with ordinal k contributes
//   ((k/800 - (k-1)/800) * (k/(i+1) + (k-1)/i)) * 0.5
// matching the reference's elementwise op order. i==0 contributes 0.
__global__ void ap_kernel(const int* __restrict__ tpCount,
                          const int* __restrict__ tpRank,
                          float* __restrict__ ap) {
    __shared__ int   sr[G];
    __shared__ float red[BS];
    const int c = blockIdx.x;
    const int T = tpCount[c];
    const int tid = threadIdx.x;
    for (int t = tid; t < T; t += BS) sr[t] = tpRank[c * G + t];
    __syncthreads();
    float sum = 0.0f;
    for (int t = tid; t < T; t += BS) {
        int r = sr[t];
        int k = 1;
        for (int u = 0; u < T; ++u) k += (sr[u] < r) ? 1 : 0;  // ranks unique
        if (r >= 1) {
            float kf  = (float)k;
            float km  = __fsub_rn(kf, 1.0f);
            float ri  = __fdiv_rn(kf, 800.0f);   // f32(800+1e-9) == 800.0f
            float rim = __fdiv_rn(km, 800.0f);
            float pi  = __fdiv_rn(kf, (float)(r + 1));
            float pim = __fdiv_rn(km, (float)r);
            sum = __fadd_rn(sum,
                  __fmul_rn(__fmul_rn(__fsub_rn(ri, rim), __fadd_rn(pi, pim)), 0.5f));
        }
    }
    red[tid] = sum;
    __syncthreads();
    for (int s = BS / 2; s > 0; s >>= 1) {
        if (tid < s) red[tid] = __fadd_rn(red[tid], red[tid + s]);
        __syncthreads();
    }
    if (tid == 0) ap[c] = red[0];
}

// ---------------- mean over classes ----------------
__global__ void mean_kernel(const float* __restrict__ ap, float* __restrict__ out) {
    if (threadIdx.x == 0) {
        float s = 0.0f;
        for (int c = 0; c < C; ++c) s = __fadd_rn(s, ap[c]);
        out[0] = __fdiv_rn(s, 80.0f);
    }
}

extern "C" void kernel_launch(void* const* d_in, const int* in_sizes, int n_in,
                              void* d_out, int out_size, void* d_ws, size_t ws_size,
                              hipStream_t stream) {
    const float* pred = (const float*)d_in[0];   // [C, P, 7] f32
    const float* gt   = (const float*)d_in[1];   // [C, G, 7] f32
    float* out = (float*)d_out;

    // Workspace layout (ws is re-poisoned 0xAA before each call; init_kernel
    // rewrites everything we read before writing).
    char* ws = (char*)d_ws;
    int*  validCount = (int*)  (ws + 0);                    //   320 B
    int*  tpCount    = (int*)  (ws + 512);                  //   320 B
    float* ap        = (float*)(ws + 1024);                 //   320 B
    int*  first      = (int*)  (ws + 2048);                 // 256000 B
    int*  tpRank     = (int*)  (ws + 2048 + 256000);        // 256000 B
    int2* validRec   = (int2*) (ws + 514048);               // 19.2 MB (8-aligned)
    int*  validRank  = (int*)  (ws + 514048 + (size_t)C * P * 8); // 9.6 MB
    // total ~29.4 MB

    init_kernel<<<dim3((C * G + BS - 1) / BS), BS, 0, stream>>>(validCount, tpCount, first);
    match_kernel<<<dim3(PBLK, C), BS, 0, stream>>>(pred, gt, validCount, validRec);
    rank_kernel<<<dim3(PBLK, C), BS, 0, stream>>>(pred, validCount, validRec, validRank, first);
    tp_kernel<<<dim3(PBLK, C), BS, 0, stream>>>(validCount, validRec, validRank, first, tpCount, tpRank);
    ap_kernel<<<C, BS, 0, stream>>>(tpCount, tpRank, ap);
    mean_kernel<<<1, 64, 0, stream>>>(ap, out);
}

// Round 2
// 1360.394 us; speedup vs baseline: 2.4385x; 2.4385x over previous
//
#include <hip/hip_runtime.h>

// Problem constants (match reference)
#define C 80
#define P 30000
#define G 800
#define BS 256

// rank order = score desc, then pred-index asc. Packed key is monotone in that
// order: (float bits of score, positive) << 32 | (P-1-p). key_a > key_b iff
// pred a sorts strictly before pred b. key==0 is "no match" (needs score==0.0
// AND p==P-1 simultaneously — probability ~0).
__device__ __forceinline__ unsigned long long pack_key(float s, int p) {
    return ((unsigned long long)__float_as_uint(s) << 32) | (unsigned)(P - 1 - p);
}

// ---------------- init: gtKey = 0, tpCount = 0 ----------------
__global__ void init_kernel(unsigned long long* __restrict__ gtKey,
                            int* __restrict__ tpCount) {
    int idx = blockIdx.x * blockDim.x + threadIdx.x;
    if (idx < C * G) gtKey[idx] = 0ull;
    if (idx < C) tpCount[idx] = 0;
}

// ---------------- match: per pred, argmax-gt IoU; atomicMax key into gt ----
// Argmax via cross-multiply: iou_g > iou_best <=> inter_g*denom_b >
// inter_b*denom_g (denoms strictly positive). First-occurrence semantics
// preserved (strict >). One correctly-rounded fdiv per PRED (not per pair)
// for the valid = iou > 0.5 test, matching the reference's rounded value.
// 2 preds/thread: halves LDS broadcast reads, doubles ILP on the update chain.
// Also extracts the score column to scoreC (compact, for the rank kernel).
__global__ __launch_bounds__(BS) void match_kernel(
        const float* __restrict__ pred, const float* __restrict__ gt,
        unsigned long long* __restrict__ gtKey, float* __restrict__ scoreC) {
    __shared__ float4 sbox[G];
    __shared__ float  sarea[G];
    const int c = blockIdx.y;
    const int tid = threadIdx.x;
    for (int g = tid; g < G; g += BS) {
        const float* gb = gt + (size_t)(c * G + g) * 7;
        float x1 = gb[3], y1 = gb[4], x2 = gb[5], y2 = gb[6];
        sbox[g] = make_float4(x1, y1, x2, y2);
        sarea[g] = __fmul_rn(__fsub_rn(x2, x1), __fsub_rn(y2, y1));
    }
    __syncthreads();

    const int p0 = blockIdx.x * (BS * 2) + tid;
    const int p1 = p0 + BS;
    if (p0 >= P) return;

    const float* pb0 = pred + (size_t)(c * P + p0) * 7;
    float s0  = pb0[2];
    float ax0 = pb0[3], ay0 = pb0[4], bx0 = pb0[5], by0 = pb0[6];
    float a0  = __fmul_rn(__fsub_rn(bx0, ax0), __fsub_rn(by0, ay0));

    const bool has1 = (p1 < P);
    float s1 = 0.f, ax1 = 0.f, ay1 = 0.f, bx1 = 0.f, by1 = 0.f, a1 = 0.f;
    if (has1) {
        const float* pb1 = pred + (size_t)(c * P + p1) * 7;
        s1  = pb1[2];
        ax1 = pb1[3]; ay1 = pb1[4]; bx1 = pb1[5]; by1 = pb1[6];
        a1  = __fmul_rn(__fsub_rn(bx1, ax1), __fsub_rn(by1, ay1));
    }

    // trackers: best inter / best denom / argmax gt. Initial (-1, 1) loses to
    // any g=0 pair (inter>=0 > -denom), reproducing argmax-from-index-0.
    float bi0 = -1.0f, bd0 = 1.0f; int m0 = 0;
    float bi1 = -1.0f, bd1 = 1.0f; int m1 = 0;

    for (int g = 0; g < G; ++g) {
        float4 b  = sbox[g];
        float  ab = sarea[g];

        float lx0 = fmaxf(ax0, b.x), ly0 = fmaxf(ay0, b.y);
        float rx0 = fminf(bx0, b.z), ry0 = fminf(by0, b.w);
        float wx0 = fmaxf(__fsub_rn(rx0, lx0), 0.0f);
        float wy0 = fmaxf(__fsub_rn(ry0, ly0), 0.0f);
        float in0 = __fmul_rn(wx0, wy0);
        float dn0 = __fadd_rn(__fsub_rn(__fadd_rn(a0, ab), in0), 1e-9f);
        bool  up0 = __fmul_rn(in0, bd0) > __fmul_rn(bi0, dn0);
        bi0 = up0 ? in0 : bi0; bd0 = up0 ? dn0 : bd0; m0 = up0 ? g : m0;

        float lx1 = fmaxf(ax1, b.x), ly1 = fmaxf(ay1, b.y);
        float rx1 = fminf(bx1, b.z), ry1 = fminf(by1, b.w);
        float wx1 = fmaxf(__fsub_rn(rx1, lx1), 0.0f);
        float wy1 = fmaxf(__fsub_rn(ry1, ly1), 0.0f);
        float in1 = __fmul_rn(wx1, wy1);
        float dn1 = __fadd_rn(__fsub_rn(__fadd_rn(a1, ab), in1), 1e-9f);
        bool  up1 = __fmul_rn(in1, bd1) > __fmul_rn(bi1, dn1);
        bi1 = up1 ? in1 : bi1; bd1 = up1 ? dn1 : bd1; m1 = up1 ? g : m1;
    }

    // one rounded division per pred: matches the reference's iou value exactly
    // for the selected pair.
    float iou0 = __fdiv_rn(bi0, bd0);
    if (iou0 > 0.5f) atomicMax(&gtKey[c * G + m0], pack_key(s0, p0));
    scoreC[(size_t)c * P + p0] = s0;
    if (has1) {
        float iou1 = __fdiv_rn(bi1, bd1);
        if (iou1 > 0.5f) atomicMax(&gtKey[c * G + m1], pack_key(s1, p1));
        scoreC[(size_t)c * P + p1] = s1;
    }
}

// ---------------- collect: one TP per matched gt ----------------
__global__ void collect_kernel(const unsigned long long* __restrict__ gtKey,
                               int* __restrict__ tpCount,
                               unsigned* __restrict__ tpScoreBits,
                               int* __restrict__ tpP) {
    int idx = blockIdx.x * blockDim.x + threadIdx.x;
    if (idx >= C * G) return;
    int c = idx / G;
    unsigned long long key = gtKey[idx];
    if (key != 0ull) {
        int slot = atomicAdd(&tpCount[c], 1);
        tpScoreBits[c * G + slot] = (unsigned)(key >> 32);
        tpP[c * G + slot] = P - 1 - (int)(key & 0xFFFFFFFFu);
    }
}

// ---------------- rank: strictly-before count for each TP ----------------
// One wave per 4 TP slots; scans the compact score column with one u64
// compare per slot per element. rank(t) = #{q : key_q > key_t}.
#define TPW 4                       // TPs per wave
#define RBLK ((G + 4 * TPW - 1) / (4 * TPW))   // blocks per class (4 waves/blk)
__global__ __launch_bounds__(BS) void rank_kernel(
        const float* __restrict__ scoreC, const int* __restrict__ tpCount,
        const unsigned* __restrict__ tpScoreBits, const int* __restrict__ tpP,
        int* __restrict__ tpRank) {
    const int c = blockIdx.y;
    const int T = tpCount[c];
    const int wid  = blockIdx.x * (BS / 64) + (threadIdx.x >> 6);
    const int lane = threadIdx.x & 63;
    const int t0 = wid * TPW;
    if (t0 >= T) return;   // wave-uniform exit

    unsigned long long k0 = ~0ull, k1 = ~0ull, k2 = ~0ull, k3 = ~0ull;
    if (t0 + 0 < T) k0 = ((unsigned long long)tpScoreBits[c * G + t0 + 0] << 32) | (unsigned)(P - 1 - tpP[c * G + t0 + 0]);
    if (t0 + 1 < T) k1 = ((unsigned long long)tpScoreBits[c * G + t0 + 1] << 32) | (unsigned)(P - 1 - tpP[c * G + t0 + 1]);
    if (t0 + 2 < T) k2 = ((unsigned long long)tpScoreBits[c * G + t0 + 2] << 32) | (unsigned)(P - 1 - tpP[c * G + t0 + 2]);
    if (t0 + 3 < T) k3 = ((unsigned long long)tpScoreBits[c * G + t0 + 3] << 32) | (unsigned)(P - 1 - tpP[c * G + t0 + 3]);

    const float* sc = scoreC + (size_t)c * P;
    int c0 = 0, c1 = 0, c2 = 0, c3 = 0;
    for (int i = lane; i < P; i += 64) {
        unsigned long long kq =
            ((unsigned long long)__float_as_uint(sc[i]) << 32) | (unsigned)(P - 1 - i);
        c0 += (kq > k0); c1 += (kq > k1); c2 += (kq > k2); c3 += (kq > k3);
    }
    for (int off = 32; off > 0; off >>= 1) {
        c0 += __shfl_down(c0, off);
        c1 += __shfl_down(c1, off);
        c2 += __shfl_down(c2, off);
        c3 += __shfl_down(c3, off);
    }
    if (lane == 0) {
        if (t0 + 0 < T) tpRank[c * G + t0 + 0] = c0;
        if (t0 + 1 < T) tpRank[c * G + t0 + 1] = c1;
        if (t0 + 2 < T) tpRank[c * G + t0 + 2] = c2;
        if (t0 + 3 < T) tpRank[c * G + t0 + 3] = c3;
    }
}

// ---------------- ap: per class, from TP ranks only ----------------
// ctp+cfp == i+1 exactly, so precision[i] = ctp[i]/(i+1) (the 1e-9 rounds
// away in f32). TP at sorted pos r (r>=1) with ordinal k contributes
// ((k/800 - (k-1)/800) * (k/(r+1) + (k-1)/r)) * 0.5 — reference op order.
__global__ void ap_kernel(const int* __restrict__ tpCount,
                          const int* __restrict__ tpRank,
                          float* __restrict__ ap) {
    __shared__ int   sr[G];
    __shared__ float red[BS];
    const int c = blockIdx.x;
    const int T = tpCount[c];
    const int tid = threadIdx.x;
    for (int t = tid; t < T; t += BS) sr[t] = tpRank[c * G + t];
    __syncthreads();
    float sum = 0.0f;
    for (int t = tid; t < T; t += BS) {
        int r = sr[t];
        int k = 1;
        for (int u = 0; u < T; ++u) k += (sr[u] < r) ? 1 : 0;  // ranks unique
        if (r >= 1) {
            float kf  = (float)k;
            float km  = __fsub_rn(kf, 1.0f);
            float ri  = __fdiv_rn(kf, 800.0f);   // f32(800+1e-9) == 800.0f
            float rim = __fdiv_rn(km, 800.0f);
            float pi  = __fdiv_rn(kf, (float)(r + 1));
            float pim = __fdiv_rn(km, (float)r);
            sum = __fadd_rn(sum,
                  __fmul_rn(__fmul_rn(__fsub_rn(ri, rim), __fadd_rn(pi, pim)), 0.5f));
        }
    }
    red[tid] = sum;
    __syncthreads();
    for (int s = BS / 2; s > 0; s >>= 1) {
        if (tid < s) red[tid] = __fadd_rn(red[tid], red[tid + s]);
        __syncthreads();
    }
    if (tid == 0) ap[c] = red[0];
}

// ---------------- mean over classes ----------------
__global__ void mean_kernel(const float* __restrict__ ap, float* __restrict__ out) {
    if (threadIdx.x == 0) {
        float s = 0.0f;
        for (int c = 0; c < C; ++c) s = __fadd_rn(s, ap[c]);
        out[0] = __fdiv_rn(s, 80.0f);
    }
}

extern "C" void kernel_launch(void* const* d_in, const int* in_sizes, int n_in,
                              void* d_out, int out_size, void* d_ws, size_t ws_size,
                              hipStream_t stream) {
    const float* pred = (const float*)d_in[0];   // [C, P, 7] f32
    const float* gt   = (const float*)d_in[1];   // [C, G, 7] f32
    float* out = (float*)d_out;

    // Workspace layout (~10.4 MB; ws re-poisoned 0xAA each call — init_kernel
    // zeroes everything that is read-before-write).
    char* ws = (char*)d_ws;
    int*                tpCount     = (int*)               (ws + 0);        //   320 B
    float*              ap          = (float*)             (ws + 512);      //   320 B
    unsigned long long* gtKey       = (unsigned long long*)(ws + 1024);     // 512000 B
    int*                tpP         = (int*)               (ws + 513024);   // 256000 B
    unsigned*           tpScoreBits = (unsigned*)          (ws + 769024);   // 256000 B
    int*                tpRank      = (int*)               (ws + 1025024);  // 256000 B
    float*              scoreC      = (float*)             (ws + 1281024);  // 9.6 MB

    init_kernel<<<dim3((C * G + BS - 1) / BS), BS, 0, stream>>>(gtKey, tpCount);
    match_kernel<<<dim3((P + 2 * BS - 1) / (2 * BS), C), BS, 0, stream>>>(pred, gt, gtKey, scoreC);
    collect_kernel<<<dim3((C * G + BS - 1) / BS), BS, 0, stream>>>(gtKey, tpCount, tpScoreBits, tpP);
    rank_kernel<<<dim3(RBLK, C), BS, 0, stream>>>(scoreC, tpCount, tpScoreBits, tpP, tpRank);
    ap_kernel<<<C, BS, 0, stream>>>(tpCount, tpRank, ap);
    mean_kernel<<<1, 64, 0, stream>>>(ap, out);
}

// Round 3
// 946.764 us; speedup vs baseline: 3.5039x; 1.4369x over previous
//
#include <hip/hip_runtime.h>

// Problem constants (match reference)
#define C 80
#define P 30000
#define G 800
#define BS 256
#define NB 8          // spatial bins per dimension (cell = 128 px, box extent <= 128)
#define NC (NB * NB)  // 64 cells per class

// rank order = score desc, then pred-index asc. Packed key is monotone in that
// order: (float bits of score, positive) << 32 | (P-1-p). key==0 means "no
// match" (needs score==0.0f AND p==P-1 — probability ~0).
__device__ __forceinline__ unsigned long long pack_key(float s, int p) {
    return ((unsigned long long)__float_as_uint(s) << 32) | (unsigned)(P - 1 - p);
}

// cell of a box by its (x1,y1); boxes span <= 2 cells/dim, so overlap partners
// of a cell-(bx,by) box lie in the 3x3 neighborhood (see proof in journal).
__device__ __forceinline__ int cell_of(float x1, float y1) {
    int bx = (int)(x1 * (1.0f / 128.0f));
    int by = (int)(y1 * (1.0f / 128.0f));
    bx = min(max(bx, 0), NB - 1);
    by = min(max(by, 0), NB - 1);
    return by * NB + bx;
}

// ---------------- init: zero everything read-before-write ----------------
__global__ void init_kernel(unsigned long long* __restrict__ gtKey,
                            int* __restrict__ tpCount,
                            int* __restrict__ gtCnt,
                            int* __restrict__ predCnt) {
    int idx = blockIdx.x * blockDim.x + threadIdx.x;
    if (idx < C * G) gtKey[idx] = 0ull;
    if (idx < C * NC) { gtCnt[idx] = 0; predCnt[idx] = 0; }
    if (idx < C) tpCount[idx] = 0;
}

// ---------------- gt binning: count ----------------
__global__ void gt_count_kernel(const float* __restrict__ gt, int* __restrict__ gtCnt) {
    int idx = blockIdx.x * blockDim.x + threadIdx.x;
    if (idx >= C * G) return;
    const float* r = gt + (size_t)idx * 7;
    int c = idx / G;
    atomicAdd(&gtCnt[c * NC + cell_of(r[3], r[4])], 1);
}

// ---------------- pred binning: count (LDS histogram per block) ----------------
__global__ void pred_count_kernel(const float* __restrict__ pred, int* __restrict__ predCnt) {
    __shared__ int h[NC];
    const int c = blockIdx.y;
    const int tid = threadIdx.x;
    if (tid < NC) h[tid] = 0;
    __syncthreads();
    int p = blockIdx.x * BS + tid;
    if (p < P) {
        const float* r = pred + ((size_t)c * P + p) * 7;
        atomicAdd(&h[cell_of(r[3], r[4])], 1);
    }
    __syncthreads();
    if (tid < NC && h[tid]) atomicAdd(&predCnt[c * NC + tid], h[tid]);
}

// ---------------- scan: per-class exclusive prefix over 64 cells ----------------
__global__ void scan_kernel(const int* __restrict__ gtCnt, int* __restrict__ gtOff,
                            int* __restrict__ gtCur,
                            const int* __restrict__ predCnt, int* __restrict__ predOff,
                            int* __restrict__ predCur) {
    int t = threadIdx.x;   // single block of 256
    if (t < C) {
        int acc = 0;
        for (int k = 0; k < NC; ++k) {
            int v = gtCnt[t * NC + k];
            gtOff[t * NC + k] = acc; gtCur[t * NC + k] = acc; acc += v;
        }
    } else if (t < 2 * C) {
        int c = t - C, acc = 0;
        for (int k = 0; k < NC; ++k) {
            int v = predCnt[c * NC + k];
            predOff[c * NC + k] = acc; predCur[c * NC + k] = acc; acc += v;
        }
    }
}

// ---------------- gt scatter: packed per-cell lists ----------------
__global__ void gt_scatter_kernel(const float* __restrict__ gt, int* __restrict__ gtCur,
                                  float4* __restrict__ gtBox, float* __restrict__ gtAbe,
                                  int* __restrict__ gtIdx) {
    int idx = blockIdx.x * blockDim.x + threadIdx.x;
    if (idx >= C * G) return;
    const float* r = gt + (size_t)idx * 7;
    float x1 = r[3], y1 = r[4], x2 = r[5], y2 = r[6];
    int c = idx / G, g = idx - c * G;
    int slot = atomicAdd(&gtCur[c * NC + cell_of(x1, y1)], 1);
    gtBox[c * G + slot] = make_float4(x1, y1, x2, y2);
    // area + eps pre-folded: cross-compare uses sb = A + (area_g + eps); the
    // -inter terms of the two denominators cancel algebraically.
    gtAbe[c * G + slot] = __fadd_rn(__fmul_rn(__fsub_rn(x2, x1), __fsub_rn(y2, y1)), 1e-9f);
    gtIdx[c * G + slot] = g;
}

// ---------------- pred scatter: per-cell index lists + compact score column ----
__global__ void pred_scatter_kernel(const float* __restrict__ pred, int* __restrict__ predCur,
                                    int* __restrict__ predIdx, float* __restrict__ scoreC) {
    const int c = blockIdx.y;
    int p = blockIdx.x * BS + threadIdx.x;
    if (p >= P) return;
    const float* r = pred + ((size_t)c * P + p) * 7;
    int slot = atomicAdd(&predCur[c * NC + cell_of(r[3], r[4])], 1);
    predIdx[(size_t)c * P + slot] = p;
    scoreC[(size_t)c * P + p] = r[2];
}

// ---------------- match: one block per (cell, class) ----------------
// 3x3 GT neighborhood staged in LDS (worst case = whole class = 800).
// Lanes of a wave share the cell -> uniform inner-loop length, no divergence.
// Argmax via cancelled cross-multiply: iou_g > iou_best <=>
// inter_g*sb_best > inter_best*sb_g with sb = A + area + eps.
// Epilogue recomputes the reference-order denominator exactly for the selected
// pair, so the >0.5 validity test uses the bit-exact reference iou.
__global__ __launch_bounds__(BS) void match2_kernel(
        const float* __restrict__ pred,
        const int* __restrict__ gtOff, const int* __restrict__ gtCnt,
        const float4* __restrict__ gtBox, const float* __restrict__ gtAbe,
        const int* __restrict__ gtIdx,
        const int* __restrict__ predOff, const int* __restrict__ predCnt,
        const int* __restrict__ predIdx,
        unsigned long long* __restrict__ gtKey) {
    __shared__ float4 sB[G];
    __shared__ float  sE[G];
    __shared__ int    sG[G];
    const int c = blockIdx.y, cell = blockIdx.x;
    const int cx = cell & (NB - 1), cy = cell >> 3;
    const int tid = threadIdx.x;

    int total = 0;
    for (int dy = -1; dy <= 1; ++dy) {
        int yy = cy + dy; if (yy < 0 || yy >= NB) continue;
        for (int dx = -1; dx <= 1; ++dx) {
            int xx = cx + dx; if (xx < 0 || xx >= NB) continue;
            int nc = yy * NB + xx;
            int off = gtOff[c * NC + nc], cnt = gtCnt[c * NC + nc];
            for (int i = tid; i < cnt; i += BS) {
                sB[total + i] = gtBox[c * G + off + i];
                sE[total + i] = gtAbe[c * G + off + i];
                sG[total + i] = gtIdx[c * G + off + i];
            }
            total += cnt;   // uniform across threads
        }
    }
    __syncthreads();

    const int pOff = predOff[c * NC + cell], pCnt = predCnt[c * NC + cell];
    for (int i = tid; i < pCnt; i += BS) {
        int p = predIdx[(size_t)c * P + pOff + i];
        const float* r = pred + ((size_t)c * P + p) * 7;
        float s   = r[2];
        float ax1 = r[3], ay1 = r[4], ax2 = r[5], ay2 = r[6];
        float A   = __fmul_rn(__fsub_rn(ax2, ax1), __fsub_rn(ay2, ay1));
        float IN = 0.0f, SB = 1.0f;
        int mj = -1;
        for (int j = 0; j < total; ++j) {
            float4 b = sB[j];
            float lx = fmaxf(ax1, b.x), ly = fmaxf(ay1, b.y);
            float rx = fminf(ax2, b.z), ry = fminf(ay2, b.w);
            float wx = fmaxf(__fsub_rn(rx, lx), 0.0f);
            float wy = fmaxf(__fsub_rn(ry, ly), 0.0f);
            float in = __fmul_rn(wx, wy);
            float sb = __fadd_rn(A, sE[j]);
            bool  up = __fmul_rn(in, SB) > __fmul_rn(IN, sb);
            IN = up ? in : IN; SB = up ? sb : SB; mj = up ? j : mj;
        }
        if (IN > 0.0f) {   // zero-inter preds can never be valid
            float4 b = sB[mj];
            float area = __fmul_rn(__fsub_rn(b.z, b.x), __fsub_rn(b.w, b.y));
            float dn = __fadd_rn(__fsub_rn(__fadd_rn(A, area), IN), 1e-9f);
            float iou = __fdiv_rn(IN, dn);   // exact reference value for this pair
            if (iou > 0.5f) atomicMax(&gtKey[c * G + sG[mj]], pack_key(s, p));
        }
    }
}

// ---------------- collect: one TP candidate per matched gt ----------------
__global__ void collect_kernel(const unsigned long long* __restrict__ gtKey,
                               int* __restrict__ tpCount,
                               unsigned* __restrict__ tpScoreBits,
                               int* __restrict__ tpP) {
    int idx = blockIdx.x * blockDim.x + threadIdx.x;
    if (idx >= C * G) return;
    int c = idx / G;
    unsigned long long key = gtKey[idx];
    if (key != 0ull) {
        int slot = atomicAdd(&tpCount[c], 1);
        tpScoreBits[c * G + slot] = (unsigned)(key >> 32);
        tpP[c * G + slot] = P - 1 - (int)(key & 0xFFFFFFFFu);
    }
}

// ---------------- rank: strictly-before count for each TP ----------------
#define TPW 4
#define RBLK ((G + 4 * TPW - 1) / (4 * TPW))
__global__ __launch_bounds__(BS) void rank_kernel(
        const float* __restrict__ scoreC, const int* __restrict__ tpCount,
        const unsigned* __restrict__ tpScoreBits, const int* __restrict__ tpP,
        int* __restrict__ tpRank) {
    const int c = blockIdx.y;
    const int T = tpCount[c];
    const int wid  = blockIdx.x * (BS / 64) + (threadIdx.x >> 6);
    const int lane = threadIdx.x & 63;
    const int t0 = wid * TPW;
    if (t0 >= T) return;   // wave-uniform exit

    unsigned long long k0 = ~0ull, k1 = ~0ull, k2 = ~0ull, k3 = ~0ull;
    if (t0 + 0 < T) k0 = ((unsigned long long)tpScoreBits[c * G + t0 + 0] << 32) | (unsigned)(P - 1 - tpP[c * G + t0 + 0]);
    if (t0 + 1 < T) k1 = ((unsigned long long)tpScoreBits[c * G + t0 + 1] << 32) | (unsigned)(P - 1 - tpP[c * G + t0 + 1]);
    if (t0 + 2 < T) k2 = ((unsigned long long)tpScoreBits[c * G + t0 + 2] << 32) | (unsigned)(P - 1 - tpP[c * G + t0 + 2]);
    if (t0 + 3 < T) k3 = ((unsigned long long)tpScoreBits[c * G + t0 + 3] << 32) | (unsigned)(P - 1 - tpP[c * G + t0 + 3]);

    const float* sc = scoreC + (size_t)c * P;
    int c0 = 0, c1 = 0, c2 = 0, c3 = 0;
    for (int i = lane; i < P; i += 64) {
        unsigned long long kq =
            ((unsigned long long)__float_as_uint(sc[i]) << 32) | (unsigned)(P - 1 - i);
        c0 += (kq > k0); c1 += (kq > k1); c2 += (kq > k2); c3 += (kq > k3);
    }
    for (int off = 32; off > 0; off >>= 1) {
        c0 += __shfl_down(c0, off);
        c1 += __shfl_down(c1, off);
        c2 += __shfl_down(c2, off);
        c3 += __shfl_down(c3, off);
    }
    if (lane == 0) {
        if (t0 + 0 < T) tpRank[c * G + t0 + 0] = c0;
        if (t0 + 1 < T) tpRank[c * G + t0 + 1] = c1;
        if (t0 + 2 < T) tpRank[c * G + t0 + 2] = c2;
        if (t0 + 3 < T) tpRank[c * G + t0 + 3] = c3;
    }
}

// ---------------- ap: per class, from TP ranks only ----------------
// ctp+cfp == i+1 exactly, so precision[i] = ctp[i]/(i+1) (the 1e-9 rounds
// away in f32). TP at sorted pos r (r>=1) with ordinal k contributes
// ((k/800 - (k-1)/800) * (k/(r+1) + (k-1)/r)) * 0.5 — reference op order.
__global__ void ap_kernel(const int* __restrict__ tpCount,
                          const int* __restrict__ tpRank,
                          float* __restrict__ ap) {
    __shared__ int   sr[G];
    __shared__ float red[BS];
    const int c = blockIdx.x;
    const int T = tpCount[c];
    const int tid = threadIdx.x;
    for (int t = tid; t < T; t += BS) sr[t] = tpRank[c * G + t];
    __syncthreads();
    float sum = 0.0f;
    for (int t = tid; t < T; t += BS) {
        int r = sr[t];
        int k = 1;
        for (int u = 0; u < T; ++u) k += (sr[u] < r) ? 1 : 0;  // ranks unique
        if (r >= 1) {
            float kf  = (float)k;
            float km  = __fsub_rn(kf, 1.0f);
            float ri  = __fdiv_rn(kf, 800.0f);
            float rim = __fdiv_rn(km, 800.0f);
            float pi  = __fdiv_rn(kf, (float)(r + 1));
            float pim = __fdiv_rn(km, (float)r);
            sum = __fadd_rn(sum,
                  __fmul_rn(__fmul_rn(__fsub_rn(ri, rim), __fadd_rn(pi, pim)), 0.5f));
        }
    }
    red[tid] = sum;
    __syncthreads();
    for (int s = BS / 2; s > 0; s >>= 1) {
        if (tid < s) red[tid] = __fadd_rn(red[tid], red[tid + s]);
        __syncthreads();
    }
    if (tid == 0) ap[c] = red[0];
}

// ---------------- mean over classes ----------------
__global__ void mean_kernel(const float* __restrict__ ap, float* __restrict__ out) {
    if (threadIdx.x == 0) {
        float s = 0.0f;
        for (int c = 0; c < C; ++c) s = __fadd_rn(s, ap[c]);
        out[0] = __fdiv_rn(s, 80.0f);
    }
}

extern "C" void kernel_launch(void* const* d_in, const int* in_sizes, int n_in,
                              void* d_out, int out_size, void* d_ws, size_t ws_size,
                              hipStream_t stream) {
    const float* pred = (const float*)d_in[0];   // [C, P, 7] f32
    const float* gt   = (const float*)d_in[1];   // [C, G, 7] f32
    float* out = (float*)d_out;

    // Workspace layout (~22.1 MB; re-poisoned 0xAA each call — init/scan
    // rewrite everything read-before-write).
    char* ws = (char*)d_ws;
    int*                tpCount     = (int*)               (ws + 0);         //    320 B
    float*              ap          = (float*)             (ws + 512);       //    320 B
    int*                gtCnt       = (int*)               (ws + 1024);      //  20480 B
    int*                gtOff       = (int*)               (ws + 21504);
    int*                gtCur       = (int*)               (ws + 41984);
    int*                predCnt     = (int*)               (ws + 62464);
    int*                predOff     = (int*)               (ws + 82944);
    int*                predCur     = (int*)               (ws + 103424);
    int*                gtIdx       = (int*)               (ws + 123904);    // 256000 B
    unsigned*           tpScoreBits = (unsigned*)          (ws + 379904);    // 256000 B
    int*                tpP         = (int*)               (ws + 635904);    // 256000 B
    int*                tpRank      = (int*)               (ws + 891904);    // 256000 B
    float*              gtAbe       = (float*)             (ws + 1147904);   // 256000 B
    float4*             gtBox       = (float4*)            (ws + 1403904);   // 1.024 MB (16-aligned)
    unsigned long long* gtKey       = (unsigned long long*)(ws + 2427904);   // 512000 B
    int*                predIdx     = (int*)               (ws + 2939904);   // 9.6 MB
    float*              scoreC      = (float*)             (ws + 12539904);  // 9.6 MB
    // end: 22139904 B

    const int CG_BLK = (C * G + BS - 1) / BS;   // 250
    const int P_BLK  = (P + BS - 1) / BS;       // 118

    init_kernel<<<CG_BLK, BS, 0, stream>>>(gtKey, tpCount, gtCnt, predCnt);
    gt_count_kernel<<<CG_BLK, BS, 0, stream>>>(gt, gtCnt);
    pred_count_kernel<<<dim3(P_BLK, C), BS, 0, stream>>>(pred, predCnt);
    scan_kernel<<<1, BS, 0, stream>>>(gtCnt, gtOff, gtCur, predCnt, predOff, predCur);
    gt_scatter_kernel<<<CG_BLK, BS, 0, stream>>>(gt, gtCur, gtBox, gtAbe, gtIdx);
    pred_scatter_kernel<<<dim3(P_BLK, C), BS, 0, stream>>>(pred, predCur, predIdx, scoreC);
    match2_kernel<<<dim3(NC, C), BS, 0, stream>>>(pred, gtOff, gtCnt, gtBox, gtAbe, gtIdx,
                                                  predOff, predCnt, predIdx, gtKey);
    collect_kernel<<<CG_BLK, BS, 0, stream>>>(gtKey, tpCount, tpScoreBits, tpP);
    rank_kernel<<<dim3(RBLK, C), BS, 0, stream>>>(scoreC, tpCount, tpScoreBits, tpP, tpRank);
    ap_kernel<<<C, BS, 0, stream>>>(tpCount, tpRank, ap);
    mean_kernel<<<1, 64, 0, stream>>>(ap, out);
}

// Round 4
// 398.167 us; speedup vs baseline: 8.3315x; 2.3778x over previous
//
#include <hip/hip_runtime.h>

// Problem constants (match reference)
#define C 80
#define P 30000
#define G 800
#define BS 256
#define NB 8          // spatial bins per dimension (cell = 128 px, box extent <= 128)
#define NC (NB * NB)  // 64 cells per class
#define HCH 8         // hist chunks per class
#define CHSZ ((P + HCH - 1) / HCH)   // 3750

// rank order = score desc, then pred-index asc. Packed key is monotone in that
// order (scores >= 0 so float bits are order-preserving): key==0 means "no
// match" (needs score==0.0f AND p==P-1 — probability ~0).
__device__ __forceinline__ unsigned long long pack_key(float s, int p) {
    return ((unsigned long long)__float_as_uint(s) << 32) | (unsigned)(P - 1 - p);
}

// cell of a box by its (x1,y1); boxes span <= 2 cells/dim, so all overlap
// partners of a cell-(bx,by) box lie in the 3x3 cell neighborhood.
__device__ __forceinline__ int cell_of(float x1, float y1) {
    int bx = (int)(x1 * (1.0f / 128.0f));
    int by = (int)(y1 * (1.0f / 128.0f));
    bx = min(max(bx, 0), NB - 1);
    by = min(max(by, 0), NB - 1);
    return by * NB + bx;
}

// ---------------- init: zero everything read-before-write ----------------
__global__ void init_kernel(unsigned long long* __restrict__ gtKey,
                            int* __restrict__ tpCount,
                            int* __restrict__ predCnt,
                            int* __restrict__ gHist) {
    int idx = blockIdx.x * blockDim.x + threadIdx.x;
    if (idx < C * G) gtKey[idx] = 0ull;
    if (idx < C * NC) predCnt[idx] = 0;
    if (idx < C * 1024) gHist[idx] = 0;
    if (idx < C) tpCount[idx] = 0;
}

// ---------------- gt binning: one block per class (count+scan+scatter) ------
__global__ __launch_bounds__(BS) void gt_bin_kernel(
        const float* __restrict__ gt,
        int* __restrict__ gtCnt, int* __restrict__ gtOff,
        float4* __restrict__ gtBox, float* __restrict__ gtAbe,
        int* __restrict__ gtIdx) {
    __shared__ int h[NC], cur[NC];
    __shared__ int gcell[G];
    const int c = blockIdx.x, tid = threadIdx.x;
    if (tid < NC) h[tid] = 0;
    __syncthreads();
    for (int i = tid; i < G; i += BS) {
        const float* r = gt + ((size_t)c * G + i) * 7;
        int cl = cell_of(r[3], r[4]);
        gcell[i] = cl;
        atomicAdd(&h[cl], 1);
    }
    __syncthreads();
    if (tid < 64) {   // wave 0: exclusive scan over 64 cells
        int v = h[tid], s = v;
        for (int o = 1; o < 64; o <<= 1) { int t = __shfl_up(s, o); if (tid >= o) s += t; }
        int excl = s - v;
        cur[tid] = excl;
        gtOff[c * NC + tid] = excl;
        gtCnt[c * NC + tid] = v;
    }
    __syncthreads();
    for (int i = tid; i < G; i += BS) {
        const float* r = gt + ((size_t)c * G + i) * 7;   // L1-hot (2nd pass)
        float x1 = r[3], y1 = r[4], x2 = r[5], y2 = r[6];
        int slot = atomicAdd(&cur[gcell[i]], 1);
        gtBox[c * G + slot] = make_float4(x1, y1, x2, y2);
        // area + eps pre-folded: cross-compare uses sb = A + (area_g + eps);
        // the -inter terms of the two denominators cancel algebraically.
        gtAbe[c * G + slot] = __fadd_rn(__fmul_rn(__fsub_rn(x2, x1), __fsub_rn(y2, y1)), 1e-9f);
        gtIdx[c * G + slot] = i;
    }
}

// ---------------- pred binning: count (LDS hist) + score extraction ----------
__global__ __launch_bounds__(BS) void pred_count_kernel(
        const float* __restrict__ pred, int* __restrict__ predCnt,
        float* __restrict__ scoreC) {
    __shared__ int h[NC];
    const int c = blockIdx.y, tid = threadIdx.x;
    if (tid < NC) h[tid] = 0;
    __syncthreads();
    int p = blockIdx.x * BS + tid;
    if (p < P) {
        const float* r = pred + ((size_t)c * P + p) * 7;
        scoreC[(size_t)c * P + p] = r[2];
        atomicAdd(&h[cell_of(r[3], r[4])], 1);
    }
    __syncthreads();
    if (tid < NC && h[tid]) atomicAdd(&predCnt[c * NC + tid], h[tid]);   // no-return
}

// ---------------- pred scan: one wave per class ----------------
__global__ void pred_scan_kernel(const int* __restrict__ predCnt,
                                 int* __restrict__ predOff, int* __restrict__ predCur) {
    const int c = blockIdx.x, lane = threadIdx.x;   // block = 64
    int v = predCnt[c * NC + lane], s = v;
    for (int o = 1; o < 64; o <<= 1) { int t = __shfl_up(s, o); if (lane >= o) s += t; }
    int excl = s - v;
    predOff[c * NC + lane] = excl;
    predCur[c * NC + lane] = excl;
}

// ---------------- pred scatter: LDS-aggregated slot reservation ----------------
// Per-element contended global return-atomics (R3's 254 us stall) replaced by:
// LDS local-rank atomic (≈4-deep chains) + ONE global atomic per (block,cell).
__global__ __launch_bounds__(BS) void pred_scatter_kernel(
        const float* __restrict__ pred, int* __restrict__ predCur,
        int* __restrict__ predP) {
    __shared__ int h[NC], base[NC];
    const int c = blockIdx.y, tid = threadIdx.x;
    if (tid < NC) h[tid] = 0;
    __syncthreads();
    int p = blockIdx.x * BS + tid;
    int cellv = 0, lr = 0;
    if (p < P) {
        const float* r = pred + ((size_t)c * P + p) * 7;
        cellv = cell_of(r[3], r[4]);
        lr = atomicAdd(&h[cellv], 1);   // LDS, local rank
    }
    __syncthreads();
    if (tid < NC && h[tid]) base[tid] = atomicAdd(&predCur[c * NC + tid], h[tid]);
    __syncthreads();
    if (p < P) predP[(size_t)c * P + base[cellv] + lr] = p;
}

// ---------------- match: one block per (cell, class) ----------------
// 3x3 GT neighborhood staged in LDS. Argmax via cancelled cross-multiply:
// iou_g > iou_best <=> inter_g*sb_best > inter_best*sb_g, sb = A + area + eps.
// Epilogue recomputes the reference-order denominator exactly for the selected
// pair, so the >0.5 validity test uses the bit-exact reference iou.
__global__ __launch_bounds__(BS) void match2_kernel(
        const float* __restrict__ pred,
        const int* __restrict__ gtOff, const int* __restrict__ gtCnt,
        const float4* __restrict__ gtBox, const float* __restrict__ gtAbe,
        const int* __restrict__ gtIdx,
        const int* __restrict__ predOff, const int* __restrict__ predCnt,
        const int* __restrict__ predP,
        unsigned long long* __restrict__ gtKey) {
    __shared__ float4 sB[G];
    __shared__ float  sE[G];
    __shared__ int    sG[G];
    const int c = blockIdx.y, cell = blockIdx.x;
    const int cx = cell & (NB - 1), cy = cell >> 3;
    const int tid = threadIdx.x;

    int total = 0;
    for (int dy = -1; dy <= 1; ++dy) {
        int yy = cy + dy; if (yy < 0 || yy >= NB) continue;
        for (int dx = -1; dx <= 1; ++dx) {
            int xx = cx + dx; if (xx < 0 || xx >= NB) continue;
            int nc = yy * NB + xx;
            int off = gtOff[c * NC + nc], cnt = gtCnt[c * NC + nc];
            for (int i = tid; i < cnt; i += BS) {
                sB[total + i] = gtBox[c * G + off + i];
                sE[total + i] = gtAbe[c * G + off + i];
                sG[total + i] = gtIdx[c * G + off + i];
            }
            total += cnt;   // uniform across threads
        }
    }
    __syncthreads();

    const int pOff = predOff[c * NC + cell], pCnt = predCnt[c * NC + cell];
    for (int i = tid; i < pCnt; i += BS) {
        int p = predP[(size_t)c * P + pOff + i];
        const float* r = pred + ((size_t)c * P + p) * 7;
        float s   = r[2];
        float ax1 = r[3], ay1 = r[4], ax2 = r[5], ay2 = r[6];
        float A   = __fmul_rn(__fsub_rn(ax2, ax1), __fsub_rn(ay2, ay1));
        float IN = 0.0f, SB = 1.0f;
        int mj = -1;
        for (int j = 0; j < total; ++j) {
            float4 b = sB[j];
            float lx = fmaxf(ax1, b.x), ly = fmaxf(ay1, b.y);
            float rx = fminf(ax2, b.z), ry = fminf(ay2, b.w);
            float wx = fmaxf(__fsub_rn(rx, lx), 0.0f);
            float wy = fmaxf(__fsub_rn(ry, ly), 0.0f);
            float in = __fmul_rn(wx, wy);
            float sb = __fadd_rn(A, sE[j]);
            bool  up = __fmul_rn(in, SB) > __fmul_rn(IN, sb);
            IN = up ? in : IN; SB = up ? sb : SB; mj = up ? j : mj;
        }
        if (IN > 0.0f) {   // zero-inter preds can never be valid
            float4 b = sB[mj];
            float area = __fmul_rn(__fsub_rn(b.z, b.x), __fsub_rn(b.w, b.y));
            float dn = __fadd_rn(__fsub_rn(__fadd_rn(A, area), IN), 1e-9f);
            float iou = __fdiv_rn(IN, dn);   // exact reference value for this pair
            if (iou > 0.5f) atomicMax(&gtKey[c * G + sG[mj]], pack_key(s, p));
        }
    }
}

// ---------------- collect: LDS-aggregated TP gather ----------------
__global__ __launch_bounds__(BS) void collect_kernel(
        const unsigned long long* __restrict__ gtKey,
        int* __restrict__ tpCount, unsigned long long* __restrict__ tpKey) {
    __shared__ int cnt, basec;
    const int c = blockIdx.y, tid = threadIdx.x;
    if (tid == 0) cnt = 0;
    __syncthreads();
    int idx = blockIdx.x * BS + tid;
    unsigned long long key = 0ull;
    int lr = 0;
    if (idx < G) key = gtKey[c * G + idx];
    if (key != 0ull) lr = atomicAdd(&cnt, 1);
    __syncthreads();
    if (tid == 0 && cnt) basec = atomicAdd(&tpCount[c], cnt);
    __syncthreads();
    if (key != 0ull) tpKey[c * G + basec + lr] = key;
}

// ---------------- sort: per class, position-sort of <=800 TP keys ----------
// O(T^2) LDS broadcast compares (~640k/class over 256 threads), scatter to a
// 1024-padded descending array (pad = 0 sorts last; real keys > 0).
__global__ __launch_bounds__(BS) void sort_kernel(
        const int* __restrict__ tpCount, const unsigned long long* __restrict__ tpKey,
        unsigned long long* __restrict__ sortedKeys) {
    __shared__ unsigned long long k[G];
    __shared__ unsigned long long sk[1024];
    const int c = blockIdx.x, tid = threadIdx.x;
    const int T = tpCount[c];
    for (int t = tid; t < T; t += BS) k[t] = tpKey[c * G + t];
    for (int j = tid; j < 1024; j += BS) sk[j] = 0ull;
    __syncthreads();
    for (int t = tid; t < T; t += BS) {
        unsigned long long key = k[t];
        int pos = 0;
        for (int u = 0; u < T; ++u) pos += (k[u] > key) ? 1 : 0;   // keys unique
        sk[pos] = key;
    }
    __syncthreads();
    for (int j = tid; j < 1024; j += BS) sortedKeys[c * 1024 + j] = sk[j];
}

// ---------------- hist: pos(q) for every pred via binary search ----------
// pos(q) = #{TP keys > key_q}; q contributes +1 to rank of every TP at sorted
// position >= pos(q). rank(s) = prefix(hist)[s] - 1 (self-count removed).
__global__ __launch_bounds__(BS) void hist_kernel(
        const float* __restrict__ scoreC,
        const unsigned long long* __restrict__ sortedKeys,
        int* __restrict__ gHist) {
    __shared__ unsigned long long sK[1024];
    __shared__ int h[1024];
    const int c = blockIdx.y, tid = threadIdx.x;
    for (int j = tid; j < 1024; j += BS) { sK[j] = sortedKeys[c * 1024 + j]; h[j] = 0; }
    __syncthreads();
    const int start = blockIdx.x * CHSZ;
    const int end   = min(start + CHSZ, P);
    const float* sc = scoreC + (size_t)c * P;
    for (int i = start + tid; i < end; i += BS) {
        unsigned long long kq =
            ((unsigned long long)__float_as_uint(sc[i]) << 32) | (unsigned)(P - 1 - i);
        int lo = 0;   // count of sorted-desc keys > kq (pads are 0, never > kq)
        #pragma unroll
        for (int step = 512; step > 0; step >>= 1)
            if (sK[lo + step - 1] > kq) lo += step;
        atomicAdd(&h[lo], 1);
    }
    __syncthreads();
    for (int j = tid; j < 1024; j += BS)
        if (h[j]) atomicAdd(&gHist[c * 1024 + j], h[j]);   // no-return
}

// ---------------- ap: prefix over hist + closed-form terms ----------------
// TP at sorted position s has ordinal k = s+1 and sorted rank r = prefix-1.
// ctp+cfp == r+1 exactly, so precision = k/(r+1) (1e-9 rounds away in f32);
// term = ((k/800 - (k-1)/800) * (k/(r+1) + (k-1)/r)) * 0.5 — reference op
// order; r == 0 contributes nothing (trapezoid starts at index 1).
__global__ __launch_bounds__(BS) void ap2_kernel(
        const int* __restrict__ tpCount, const int* __restrict__ gHist,
        float* __restrict__ ap) {
    __shared__ int hా[1024];
    __shared__ int hb[1024];
    __shared__ float red[BS];
    const int c = blockIdx.x, tid = threadIdx.x;
    const int T = tpCount[c];
    for (int j = tid; j < 1024; j += BS) hా[j] = gHist[c * 1024 + j];
    __syncthreads();
    int* src = hా; int* dst = hb;
    for (int o = 1; o < 1024; o <<= 1) {
        for (int j = tid; j < 1024; j += BS)
            dst[j] = src[j] + ((j >= o) ? src[j - o] : 0);
        __syncthreads();
        int* tmp = src; src = dst; dst = tmp;
    }
    float sum = 0.0f;
    for (int s = tid; s < T; s += BS) {
        int r = src[s] - 1;          // inclusive prefix minus self
        if (r >= 1) {
            float kf  = (float)(s + 1);
            float km  = (float)s;
            float ri  = __fdiv_rn(kf, 800.0f);
            float rim = __fdiv_rn(km, 800.0f);
            float pi  = __fdiv_rn(kf, (float)(r + 1));
            float pim = __fdiv_rn(km, (float)r);
            sum = __fadd_rn(sum,
                  __fmul_rn(__fmul_rn(__fsub_rn(ri, rim), __fadd_rn(pi, pim)), 0.5f));
        }
    }
    red[tid] = sum;
    __syncthreads();
    for (int s2 = BS / 2; s2 > 0; s2 >>= 1) {
        if (tid < s2) red[tid] = __fadd_rn(red[tid], red[tid + s2]);
        __syncthreads();
    }
    if (tid == 0) ap[c] = red[0];
}

// ---------------- mean over classes ----------------
__global__ void mean_kernel(const float* __restrict__ ap, float* __restrict__ out) {
    if (threadIdx.x == 0) {
        float s = 0.0f;
        for (int c = 0; c < C; ++c) s = __fadd_rn(s, ap[c]);
        out[0] = __fdiv_rn(s, 80.0f);
    }
}

extern "C" void kernel_launch(void* const* d_in, const int* in_sizes, int n_in,
                              void* d_out, int out_size, void* d_ws, size_t ws_size,
                              hipStream_t stream) {
    const float* pred = (const float*)d_in[0];   // [C, P, 7] f32
    const float* gt   = (const float*)d_in[1];   // [C, G, 7] f32
    float* out = (float*)d_out;

    // Workspace layout (~22.8 MB; re-poisoned 0xAA each call — init/gt_bin/
    // pred_scan rewrite everything read-before-write).
    char* ws = (char*)d_ws;
    int*                tpCount    = (int*)               (ws + 0);         //    320 B
    float*              ap         = (float*)             (ws + 512);       //    320 B
    int*                predCnt    = (int*)               (ws + 1024);      //  20480 B
    int*                predOff    = (int*)               (ws + 21504);
    int*                predCur    = (int*)               (ws + 41984);
    int*                gtCnt      = (int*)               (ws + 62464);
    int*                gtOff      = (int*)               (ws + 82944);
    int*                gtIdx      = (int*)               (ws + 103424);    // 256000 B
    float*              gtAbe      = (float*)             (ws + 359424);    // 256000 B
    float4*             gtBox      = (float4*)            (ws + 615424);    // 1.024 MB (16-aligned)
    unsigned long long* gtKey      = (unsigned long long*)(ws + 1639424);   // 512000 B
    unsigned long long* tpKey      = (unsigned long long*)(ws + 2151424);   // 512000 B
    unsigned long long* sortedKeys = (unsigned long long*)(ws + 2663424);   // 655360 B
    int*                gHist      = (int*)               (ws + 3318784);   // 327680 B
    int*                predP      = (int*)               (ws + 3646464);   // 9.6 MB
    float*              scoreC     = (float*)             (ws + 13246464);  // 9.6 MB
    // end: 22846464 B

    const int P_BLK = (P + BS - 1) / BS;   // 118

    init_kernel<<<(C * 1024 + BS - 1) / BS, BS, 0, stream>>>(gtKey, tpCount, predCnt, gHist);
    gt_bin_kernel<<<C, BS, 0, stream>>>(gt, gtCnt, gtOff, gtBox, gtAbe, gtIdx);
    pred_count_kernel<<<dim3(P_BLK, C), BS, 0, stream>>>(pred, predCnt, scoreC);
    pred_scan_kernel<<<C, 64, 0, stream>>>(predCnt, predOff, predCur);
    pred_scatter_kernel<<<dim3(P_BLK, C), BS, 0, stream>>>(pred, predCur, predP);
    match2_kernel<<<dim3(NC, C), BS, 0, stream>>>(pred, gtOff, gtCnt, gtBox, gtAbe, gtIdx,
                                                  predOff, predCnt, predP, gtKey);
    collect_kernel<<<dim3((G + BS - 1) / BS, C), BS, 0, stream>>>(gtKey, tpCount, tpKey);
    sort_kernel<<<C, BS, 0, stream>>>(tpCount, tpKey, sortedKeys);
    hist_kernel<<<dim3(HCH, C), BS, 0, stream>>>(scoreC, sortedKeys, gHist);
    ap2_kernel<<<C, BS, 0, stream>>>(tpCount, gHist, ap);
    mean_kernel<<<1, 64, 0, stream>>>(ap, out);
}

// Round 5
// 386.708 us; speedup vs baseline: 8.5784x; 1.0296x over previous
//
#include <hip/hip_runtime.h>

// Problem constants (match reference)
#define C 80
#define P 30000
#define G 800
#define BS 256
#define NB 8          // spatial bins per dimension (cell = 128 px, box extent <= 128)
#define NC (NB * NB)  // 64 cells per class
#define NCH 3         // pred chunks per cell in match (612 avg preds/cell -> <=768 typical)
#define HCH 8         // hist chunks per class
#define CHSZ ((P + HCH - 1) / HCH)   // 3750

// rank order = score desc, then pred-index asc. Packed key is monotone in that
// order (scores >= 0 so float bits are order-preserving). key==0 means "no
// match" (needs score==0.0f AND p==P-1 — probability ~0).
__device__ __forceinline__ unsigned long long pack_key(float s, int p) {
    return ((unsigned long long)__float_as_uint(s) << 32) | (unsigned)(P - 1 - p);
}

// cell of a box by its (x1,y1); boxes span <= 2 cells/dim, so all overlap
// partners of a cell-(bx,by) box lie in the 3x3 cell neighborhood.
__device__ __forceinline__ int cell_of(float x1, float y1) {
    int bx = (int)(x1 * (1.0f / 128.0f));
    int by = (int)(y1 * (1.0f / 128.0f));
    bx = min(max(bx, 0), NB - 1);
    by = min(max(by, 0), NB - 1);
    return by * NB + bx;
}

// ---------------- init: zero everything read-before-write ----------------
__global__ void init_kernel(unsigned long long* __restrict__ gtKey,
                            int* __restrict__ predCnt,
                            int* __restrict__ gHist) {
    int idx = blockIdx.x * blockDim.x + threadIdx.x;
    if (idx < C * G) gtKey[idx] = 0ull;
    if (idx < C * NC) predCnt[idx] = 0;
    if (idx < C * 1024) gHist[idx] = 0;
}

// ---------------- gt binning: one block per class (count+scan+scatter) ------
__global__ __launch_bounds__(BS) void gt_bin_kernel(
        const float* __restrict__ gt,
        int* __restrict__ gtCnt, int* __restrict__ gtOff,
        float4* __restrict__ gtBox, float* __restrict__ gtAbe,
        int* __restrict__ gtIdx) {
    __shared__ int h[NC], cur[NC];
    __shared__ int gcell[G];
    const int c = blockIdx.x, tid = threadIdx.x;
    if (tid < NC) h[tid] = 0;
    __syncthreads();
    for (int i = tid; i < G; i += BS) {
        const float* r = gt + ((size_t)c * G + i) * 7;
        int cl = cell_of(r[3], r[4]);
        gcell[i] = cl;
        atomicAdd(&h[cl], 1);
    }
    __syncthreads();
    if (tid < 64) {   // wave 0: exclusive scan over 64 cells
        int v = h[tid], s = v;
        for (int o = 1; o < 64; o <<= 1) { int t = __shfl_up(s, o); if (tid >= o) s += t; }
        int excl = s - v;
        cur[tid] = excl;
        gtOff[c * NC + tid] = excl;
        gtCnt[c * NC + tid] = v;
    }
    __syncthreads();
    for (int i = tid; i < G; i += BS) {
        const float* r = gt + ((size_t)c * G + i) * 7;   // L1-hot (2nd pass)
        float x1 = r[3], y1 = r[4], x2 = r[5], y2 = r[6];
        int slot = atomicAdd(&cur[gcell[i]], 1);
        gtBox[c * G + slot] = make_float4(x1, y1, x2, y2);
        // area + eps pre-folded: cross-compare uses sb = A + (area_g + eps);
        // the -inter terms of the two denominators cancel algebraically.
        gtAbe[c * G + slot] = __fadd_rn(__fmul_rn(__fsub_rn(x2, x1), __fsub_rn(y2, y1)), 1e-9f);
        gtIdx[c * G + slot] = i;
    }
}

// ---------------- pred prep: count hist + score extraction + cell cache ------
__global__ __launch_bounds__(BS) void pred_prep_kernel(
        const float* __restrict__ pred, int* __restrict__ predCnt,
        float* __restrict__ scoreC, unsigned char* __restrict__ cellB) {
    __shared__ int h[NC];
    const int c = blockIdx.y, tid = threadIdx.x;
    if (tid < NC) h[tid] = 0;
    __syncthreads();
    int p = blockIdx.x * BS + tid;
    if (p < P) {
        const float* r = pred + ((size_t)c * P + p) * 7;
        scoreC[(size_t)c * P + p] = r[2];
        int cl = cell_of(r[3], r[4]);
        cellB[(size_t)c * P + p] = (unsigned char)cl;
        atomicAdd(&h[cl], 1);
    }
    __syncthreads();
    if (tid < NC && h[tid]) atomicAdd(&predCnt[c * NC + tid], h[tid]);   // no-return
}

// ---------------- pred scan: one wave per class ----------------
__global__ void pred_scan_kernel(const int* __restrict__ predCnt,
                                 int* __restrict__ predOff, int* __restrict__ predCur) {
    const int c = blockIdx.x, lane = threadIdx.x;   // block = 64
    int v = predCnt[c * NC + lane], s = v;
    for (int o = 1; o < 64; o <<= 1) { int t = __shfl_up(s, o); if (lane >= o) s += t; }
    int excl = s - v;
    predOff[c * NC + lane] = excl;
    predCur[c * NC + lane] = excl;
}

// ---------------- pred scatter: cellB-only read, LDS-aggregated slots -------
__global__ __launch_bounds__(BS) void pred_scatter_kernel(
        const unsigned char* __restrict__ cellB, int* __restrict__ predCur,
        int* __restrict__ predP) {
    __shared__ int h[NC], base[NC];
    const int c = blockIdx.y, tid = threadIdx.x;
    if (tid < NC) h[tid] = 0;
    __syncthreads();
    int p = blockIdx.x * BS + tid;
    int cellv = 0, lr = 0;
    if (p < P) {
        cellv = cellB[(size_t)c * P + p];
        lr = atomicAdd(&h[cellv], 1);   // LDS, local rank
    }
    __syncthreads();
    if (tid < NC && h[tid]) base[tid] = atomicAdd(&predCur[c * NC + tid], h[tid]);
    __syncthreads();
    if (p < P) predP[(size_t)c * P + base[cellv] + lr] = p;
}

// ---------------- match: block per (cell, class, pred-chunk) ----------------
// 3x3 GT neighborhood staged in LDS. Argmax via cancelled cross-multiply:
// iou_g > iou_best <=> inter_g*sb_best > inter_best*sb_g, sb = A + area + eps.
// Epilogue recomputes the reference-order denominator exactly for the selected
// pair, so the >0.5 validity test uses the bit-exact reference iou.
// z-chunking (NCH x 256 preds) balances block durations; stride loop covers
// any cell with > NCH*BS preds.
__global__ __launch_bounds__(BS) void match2_kernel(
        const float* __restrict__ pred,
        const int* __restrict__ gtOff, const int* __restrict__ gtCnt,
        const float4* __restrict__ gtBox, const float* __restrict__ gtAbe,
        const int* __restrict__ gtIdx,
        const int* __restrict__ predOff, const int* __restrict__ predCnt,
        const int* __restrict__ predP,
        unsigned long long* __restrict__ gtKey) {
    __shared__ float4 sB[G];
    __shared__ float  sE[G];
    __shared__ int    sG[G];
    const int c = blockIdx.y, cell = blockIdx.x;
    const int tid = threadIdx.x;

    const int pOff = predOff[c * NC + cell], pCnt = predCnt[c * NC + cell];
    if (blockIdx.z * BS >= pCnt) return;   // block-uniform early exit

    const int cx = cell & (NB - 1), cy = cell >> 3;
    int total = 0;
    for (int dy = -1; dy <= 1; ++dy) {
        int yy = cy + dy; if (yy < 0 || yy >= NB) continue;
        for (int dx = -1; dx <= 1; ++dx) {
            int xx = cx + dx; if (xx < 0 || xx >= NB) continue;
            int nc = yy * NB + xx;
            int off = gtOff[c * NC + nc], cnt = gtCnt[c * NC + nc];
            for (int i = tid; i < cnt; i += BS) {
                sB[total + i] = gtBox[c * G + off + i];
                sE[total + i] = gtAbe[c * G + off + i];
                sG[total + i] = gtIdx[c * G + off + i];
            }
            total += cnt;   // uniform across threads
        }
    }
    __syncthreads();

    for (int i = blockIdx.z * BS + tid; i < pCnt; i += NCH * BS) {
        int p = predP[(size_t)c * P + pOff + i];
        const float* r = pred + ((size_t)c * P + p) * 7;
        float ax1 = r[3], ay1 = r[4], ax2 = r[5], ay2 = r[6];
        float A   = __fmul_rn(__fsub_rn(ax2, ax1), __fsub_rn(ay2, ay1));
        float IN = 0.0f, SB = 1.0f;
        int mj = -1;
        #pragma unroll 4
        for (int j = 0; j < total; ++j) {
            float4 b = sB[j];
            float lx = fmaxf(ax1, b.x), ly = fmaxf(ay1, b.y);
            float rx = fminf(ax2, b.z), ry = fminf(ay2, b.w);
            float wx = fmaxf(__fsub_rn(rx, lx), 0.0f);
            float wy = fmaxf(__fsub_rn(ry, ly), 0.0f);
            float in = __fmul_rn(wx, wy);
            float sb = __fadd_rn(A, sE[j]);
            bool  up = __fmul_rn(in, SB) > __fmul_rn(IN, sb);
            IN = up ? in : IN; SB = up ? sb : SB; mj = up ? j : mj;
        }
        if (IN > 0.0f) {   // zero-inter preds can never be valid
            float4 b = sB[mj];
            float area = __fmul_rn(__fsub_rn(b.z, b.x), __fsub_rn(b.w, b.y));
            float dn = __fadd_rn(__fsub_rn(__fadd_rn(A, area), IN), 1e-9f);
            float iou = __fdiv_rn(IN, dn);   // exact reference value for this pair
            if (iou > 0.5f) {
                float s = r[2];              // rare path: load score only here
                atomicMax(&gtKey[c * G + sG[mj]], pack_key(s, p));
            }
        }
    }
}

// ---------------- sortc: compact gtKey + position-sort, one block/class -----
// Compaction via LDS atomic; O(T^2) broadcast position-sort (T <= 800, keys
// unique); scatter to a 1024-padded descending array (pad = 0 sorts last).
__global__ __launch_bounds__(BS) void sortc_kernel(
        const unsigned long long* __restrict__ gtKey,
        unsigned long long* __restrict__ sortedKeys, int* __restrict__ sortT) {
    __shared__ unsigned long long k[G];
    __shared__ unsigned long long sk[1024];
    __shared__ int cnt;
    const int c = blockIdx.x, tid = threadIdx.x;
    if (tid == 0) cnt = 0;
    for (int j = tid; j < 1024; j += BS) sk[j] = 0ull;
    __syncthreads();
    for (int i = tid; i < G; i += BS) {
        unsigned long long key = gtKey[c * G + i];
        if (key != 0ull) k[atomicAdd(&cnt, 1)] = key;
    }
    __syncthreads();
    const int T = cnt;
    if (tid == 0) sortT[c] = T;
    for (int t = tid; t < T; t += BS) {
        unsigned long long key = k[t];
        int pos = 0;
        for (int u = 0; u < T; ++u) pos += (k[u] > key) ? 1 : 0;   // keys unique
        sk[pos] = key;
    }
    __syncthreads();
    for (int j = tid; j < 1024; j += BS) sortedKeys[c * 1024 + j] = sk[j];
}

// ---------------- hist: pos(q) for every pred via binary search ----------
// pos(q) = #{TP keys > key_q}; q contributes +1 to rank of every TP at sorted
// position >= pos(q). rank(s) = prefix(hist)[s] - 1 (self-count removed).
__global__ __launch_bounds__(BS) void hist_kernel(
        const float* __restrict__ scoreC,
        const unsigned long long* __restrict__ sortedKeys,
        int* __restrict__ gHist) {
    __shared__ unsigned long long sK[1024];
    __shared__ int h[1024];
    const int c = blockIdx.y, tid = threadIdx.x;
    for (int j = tid; j < 1024; j += BS) { sK[j] = sortedKeys[c * 1024 + j]; h[j] = 0; }
    __syncthreads();
    const int start = blockIdx.x * CHSZ;
    const int end   = min(start + CHSZ, P);
    const float* sc = scoreC + (size_t)c * P;
    for (int i = start + tid; i < end; i += BS) {
        unsigned long long kq =
            ((unsigned long long)__float_as_uint(sc[i]) << 32) | (unsigned)(P - 1 - i);
        int lo = 0;   // count of sorted-desc keys > kq (pads are 0, never > kq)
        #pragma unroll
        for (int step = 512; step > 0; step >>= 1)
            if (sK[lo + step - 1] > kq) lo += step;
        atomicAdd(&h[lo], 1);
    }
    __syncthreads();
    for (int j = tid; j < 1024; j += BS)
        if (h[j]) atomicAdd(&gHist[c * 1024 + j], h[j]);   // no-return
}

// ---------------- ap: prefix over hist + closed-form terms ----------------
// TP at sorted position s has ordinal k = s+1 and sorted rank r = prefix-1.
// ctp+cfp == r+1 exactly, so precision = k/(r+1) (1e-9 rounds away in f32);
// term = ((k/800 - (k-1)/800) * (k/(r+1) + (k-1)/r)) * 0.5 — reference op
// order; r == 0 contributes nothing (trapezoid starts at index 1).
__global__ __launch_bounds__(BS) void ap2_kernel(
        const int* __restrict__ sortT, const int* __restrict__ gHist,
        float* __restrict__ ap) {
    __shared__ int ha[1024];
    __shared__ int hb[1024];
    __shared__ float red[BS];
    const int c = blockIdx.x, tid = threadIdx.x;
    const int T = sortT[c];
    for (int j = tid; j < 1024; j += BS) ha[j] = gHist[c * 1024 + j];
    __syncthreads();
    int* src = ha; int* dst = hb;
    for (int o = 1; o < 1024; o <<= 1) {
        for (int j = tid; j < 1024; j += BS)
            dst[j] = src[j] + ((j >= o) ? src[j - o] : 0);
        __syncthreads();
        int* tmp = src; src = dst; dst = tmp;
    }
    float sum = 0.0f;
    for (int s = tid; s < T; s += BS) {
        int r = src[s] - 1;          // inclusive prefix minus self
        if (r >= 1) {
            float kf  = (float)(s + 1);
            float km  = (float)s;
            float ri  = __fdiv_rn(kf, 800.0f);
            float rim = __fdiv_rn(km, 800.0f);
            float pi  = __fdiv_rn(kf, (float)(r + 1));
            float pim = __fdiv_rn(km, (float)r);
            sum = __fadd_rn(sum,
                  __fmul_rn(__fmul_rn(__fsub_rn(ri, rim), __fadd_rn(pi, pim)), 0.5f));
        }
    }
    red[tid] = sum;
    __syncthreads();
    for (int s2 = BS / 2; s2 > 0; s2 >>= 1) {
        if (tid < s2) red[tid] = __fadd_rn(red[tid], red[tid + s2]);
        __syncthreads();
    }
    if (tid == 0) ap[c] = red[0];
}

// ---------------- mean over classes ----------------
__global__ void mean_kernel(const float* __restrict__ ap, float* __restrict__ out) {
    if (threadIdx.x == 0) {
        float s = 0.0f;
        for (int c = 0; c < C; ++c) s = __fadd_rn(s, ap[c]);
        out[0] = __fdiv_rn(s, 80.0f);
    }
}

extern "C" void kernel_launch(void* const* d_in, const int* in_sizes, int n_in,
                              void* d_out, int out_size, void* d_ws, size_t ws_size,
                              hipStream_t stream) {
    const float* pred = (const float*)d_in[0];   // [C, P, 7] f32
    const float* gt   = (const float*)d_in[1];   // [C, G, 7] f32
    float* out = (float*)d_out;

    // Workspace layout (~25.1 MB; re-poisoned 0xAA each call — init/gt_bin/
    // pred_scan/sortc rewrite everything read-before-write).
    char* ws = (char*)d_ws;
    int*                sortT      = (int*)               (ws + 0);         //    320 B
    float*              ap         = (float*)             (ws + 512);       //    320 B
    int*                predCnt    = (int*)               (ws + 1024);      //  20480 B
    int*                predOff    = (int*)               (ws + 21504);
    int*                predCur    = (int*)               (ws + 41984);
    int*                gtCnt      = (int*)               (ws + 62464);
    int*                gtOff      = (int*)               (ws + 82944);
    int*                gtIdx      = (int*)               (ws + 103424);    // 256000 B
    float*              gtAbe      = (float*)             (ws + 359424);    // 256000 B
    float4*             gtBox      = (float4*)            (ws + 615424);    // 1.024 MB (16-aligned)
    unsigned long long* gtKey      = (unsigned long long*)(ws + 1639424);   // 512000 B
    unsigned long long* sortedKeys = (unsigned long long*)(ws + 2151424);   // 655360 B
    int*                gHist      = (int*)               (ws + 2806784);   // 327680 B
    unsigned char*      cellB      = (unsigned char*)     (ws + 3134464);   // 2.4 MB
    int*                predP      = (int*)               (ws + 5534464);   // 9.6 MB
    float*              scoreC     = (float*)             (ws + 15134464);  // 9.6 MB
    // end: 24734464 B

    const int P_BLK = (P + BS - 1) / BS;   // 118

    init_kernel<<<(C * 1024 + BS - 1) / BS, BS, 0, stream>>>(gtKey, predCnt, gHist);
    gt_bin_kernel<<<C, BS, 0, stream>>>(gt, gtCnt, gtOff, gtBox, gtAbe, gtIdx);
    pred_prep_kernel<<<dim3(P_BLK, C), BS, 0, stream>>>(pred, predCnt, scoreC, cellB);
    pred_scan_kernel<<<C, 64, 0, stream>>>(predCnt, predOff, predCur);
    pred_scatter_kernel<<<dim3(P_BLK, C), BS, 0, stream>>>(cellB, predCur, predP);
    match2_kernel<<<dim3(NC, C, NCH), BS, 0, stream>>>(pred, gtOff, gtCnt, gtBox, gtAbe, gtIdx,
                                                       predOff, predCnt, predP, gtKey);
    sortc_kernel<<<C, BS, 0, stream>>>(gtKey, sortedKeys, sortT);
    hist_kernel<<<dim3(HCH, C), BS, 0, stream>>>(scoreC, sortedKeys, gHist);
    ap2_kernel<<<C, BS, 0, stream>>>(sortT, gHist, ap);
    mean_kernel<<<1, 64, 0, stream>>>(ap, out);
}